// Round 11
// baseline (269.404 us; speedup 1.0000x reference)
//
#include <hip/hip_runtime.h>
#include <hip/hip_bf16.h>

// GIN: 3x fused [CSR gather-sum + MLP(64->64->64) + relu] + mean-pool(128) + linear(64->10)
// v11:
//  gmlp: BARRIER-FREE independent waves. 6250 x 128-thr blocks; each wave owns 8
//   rows end-to-end: gather (v5 G8 pipelines) -> own LDS region -> full 16x64 MLP
//   on a half-filled MFMA tile (rows 8-15 garbage, never stored) -> store/pool.
//   Zero __syncthreads: removes wave-pair skew stalls (2.63 vs ~3.0 TB/s gap at
//   constant BW/occ). LDS 9.2KB/block, still 16 blocks/CU.
//  prep: tobf + binA fused (independent work, role-split by blockIdx; binA hides
//   under tobf streaming). bcnt zeroed by hipMemsetAsync (capture-safe).
//  sortfill: 1024 threads (391 blocks -> 24 waves/CU latency hiding).
// 7 dispatches (memset + prep + sortfill + 3 gmlp + cls).

#define N_NODES 100000
#define N_EDGES 1200000
#define N_GRAPH 128
#define N_CLS   10
#define NBUCK   391        // dst >> 8
#define BCAP    4096       // per-bucket capacity (mean 3070, +18 sigma)
#define BSH     12         // log2(BCAP)
#define NTILES  6250       // N_NODES / 16
#define TOBF_BLKS 1563     // ceil(N_NODES*64 / (512*8))
#define BINA_BLKS 586      // ceil(N_EDGES/4 / 512)

typedef __bf16 bf16_t;
typedef __bf16 bf16x8 __attribute__((ext_vector_type(8)));
typedef float  f32x4  __attribute__((ext_vector_type(4)));

// ---------------- prep: x->bf16 + binA fused (+ gsum/pads zero, wfrag pack) ----------------
__global__ void prep_kernel(const float* __restrict__ x, bf16_t* __restrict__ xb,
                            int* __restrict__ bcnt, float* __restrict__ gsum,
                            const float* __restrict__ w1a, const float* __restrict__ w1b,
                            const float* __restrict__ w2a, const float* __restrict__ w2b,
                            const float* __restrict__ w3a, const float* __restrict__ w3b,
                            bf16_t* __restrict__ wfragG,
                            bf16_t* __restrict__ hPad, bf16_t* __restrict__ xAPad,
                            const int* __restrict__ ei, int* __restrict__ bpair) {
    __shared__ int lcnt[NBUCK];
    __shared__ int lbase[NBUCK];
    const int tid = threadIdx.x;
    const int blk = blockIdx.x;

    if (blk >= TOBF_BLKS) {
        // ---- binA role (bcnt pre-zeroed by hipMemsetAsync) ----
        for (int b = tid; b < NBUCK; b += 512) lcnt[b] = 0;
        __syncthreads();
        const int e0 = ((blk - TOBF_BLKS) * 512 + tid) * 4;
        int4 s4, d4; int b[4], r[4];
        const bool valid = e0 < N_EDGES;           // N_EDGES % 4 == 0
        if (valid) {
            s4 = *(const int4*)(ei + e0);
            d4 = *(const int4*)(ei + N_EDGES + e0);
            b[0] = d4.x >> 8; b[1] = d4.y >> 8; b[2] = d4.z >> 8; b[3] = d4.w >> 8;
            r[0] = atomicAdd(&lcnt[b[0]], 1);
            r[1] = atomicAdd(&lcnt[b[1]], 1);
            r[2] = atomicAdd(&lcnt[b[2]], 1);
            r[3] = atomicAdd(&lcnt[b[3]], 1);
        }
        __syncthreads();
        for (int bb = tid; bb < NBUCK; bb += 512) {
            const int c = lcnt[bb];
            lbase[bb] = c ? atomicAdd(&bcnt[bb], c) : 0;
        }
        __syncthreads();
        if (valid) {
            const int ss[4] = {s4.x, s4.y, s4.z, s4.w};
            const int dd[4] = {d4.x, d4.y, d4.z, d4.w};
#pragma unroll
            for (int j = 0; j < 4; ++j) {
                const int slot = lbase[b[j]] + r[j];
                if (slot < BCAP)
                    bpair[(b[j] << BSH) + slot] = (ss[j] << 8) | (dd[j] & 255);
            }
        }
        return;
    }

    // ---- special roles (blocks 0..3 also convert their x slice) ----
    if (blk == 0) {
        f32x4* g4 = (f32x4*)gsum;
        for (int i = tid; i < N_GRAPH * 16; i += 512)   // 8192 f32
            g4[i] = (f32x4){0.f, 0.f, 0.f, 0.f};
        if (tid < 64) {                                  // zero-pad rows (idx N_NODES)
            xb[N_NODES * 64 + tid]    = (bf16_t)0.f;
            hPad[N_NODES * 64 + tid]  = (bf16_t)0.f;
            xAPad[N_NODES * 64 + tid] = (bf16_t)0.f;
        }
    } else if (blk <= 3 && tid < 256) {
        // pack layer L's weight fragments: wfragG[((L*2+m)*8+fi)*512 + lane*8 + j]
        const int L = blk - 1;
        const float* wA = L == 0 ? w1a : (L == 1 ? w2a : w3a);
        const float* wB = L == 0 ? w1b : (L == 1 ? w2b : w3b);
        const int k  = tid >> 2;
        const int n0 = (tid & 3) << 4;
        const int ks = k >> 5, qd = (k >> 3) & 3, jj = k & 7;
        const int fi = ((n0 >> 4) << 1) + ks;
#pragma unroll
        for (int m = 0; m < 2; ++m) {
            const float* w = m ? wB : wA;
            const f32x4 v0 = *(const f32x4*)(w + k * 64 + n0);
            const f32x4 v1 = *(const f32x4*)(w + k * 64 + n0 + 4);
            const f32x4 v2 = *(const f32x4*)(w + k * 64 + n0 + 8);
            const f32x4 v3 = *(const f32x4*)(w + k * 64 + n0 + 12);
            bf16_t* dst = wfragG + ((L * 2 + m) * 8 + fi) * 512 + jj;
#pragma unroll
            for (int l = 0; l < 4; ++l) {
                dst[(qd * 16 + l) * 8]      = (bf16_t)v0[l];
                dst[(qd * 16 + 4 + l) * 8]  = (bf16_t)v1[l];
                dst[(qd * 16 + 8 + l) * 8]  = (bf16_t)v2[l];
                dst[(qd * 16 + 12 + l) * 8] = (bf16_t)v3[l];
            }
        }
    }

    // ---- tobf stream ----
    const int i = (blk * 512 + tid) * 8;
    if (i < N_NODES * 64) {
        const f32x4 a = *(const f32x4*)(x + i);
        const f32x4 b = *(const f32x4*)(x + i + 4);
        bf16x8 o;
#pragma unroll
        for (int j = 0; j < 4; ++j) { o[j] = (bf16_t)a[j]; o[4 + j] = (bf16_t)b[j]; }
        *(bf16x8*)(xb + i) = o;
    }
}

// one WG (1024 threads) per bucket: inline prefix + LDS counting sort
__global__ void sortfill_kernel(const int* __restrict__ bpair,
                                const int* __restrict__ bcnt,
                                int* __restrict__ offset, int* __restrict__ csr) {
    __shared__ int red[1024];
    __shared__ int hist[256];
    __shared__ int l[256];
    __shared__ int cursor[256];
    const int b = blockIdx.x;
    const int t = threadIdx.x;
    const int base = b << BSH;

    // prefix: cbase = sum_{i<b} min(bcnt[i],BCAP); cnt = min(bcnt[b],BCAP)
    int part = 0;
    for (int i = t; i < b; i += 1024) {
        int c = bcnt[i];
        part += (c < BCAP ? c : BCAP);
    }
    red[t] = part;
    __syncthreads();
    for (int d = 512; d > 0; d >>= 1) {
        if (t < d) red[t] += red[t + d];
        __syncthreads();
    }
    const int cbase = red[0];
    int cnt = bcnt[b];
    cnt = cnt < BCAP ? cnt : BCAP;
    if (b == NBUCK - 1 && t == 0) offset[N_NODES] = cbase + cnt;
    __syncthreads();

    if (t < 256) hist[t] = 0;
    __syncthreads();
    for (int i = t; i < cnt; i += 1024)
        atomicAdd(&hist[bpair[base + i] & 255], 1);
    __syncthreads();

    int v = 0;
    if (t < 256) { v = hist[t]; l[t] = v; }
    __syncthreads();
    for (int d = 1; d < 256; d <<= 1) {
        int u = 0;
        if (t < 256) { u = l[t]; if (t >= d) u += l[t - d]; }
        __syncthreads();
        if (t < 256) l[t] = u;
        __syncthreads();
    }
    if (t < 256) {
        const int gpos = cbase + l[t] - v;          // exclusive
        const int node = (b << 8) + t;
        if (node < N_NODES) offset[node] = gpos;
        cursor[t] = gpos;
    }
    __syncthreads();

    for (int i = t; i < cnt; i += 1024) {
        const int p = bpair[base + i];
        const int pos = atomicAdd(&cursor[p & 255], 1);
        csr[pos] = p >> 8;
    }
}

// ---------------------------------------------------------------------------
// Unmasked 8-deep gather group. Indices beyond a row's count are N_NODES ->
// the zero pad row (L1-hot, contributes 0).
// ---------------------------------------------------------------------------
#define G8(S, J, ACC)                                                          \
    {                                                                          \
        const int t0 = __shfl(S, (J) + 0), t1 = __shfl(S, (J) + 1);            \
        const int t2 = __shfl(S, (J) + 2), t3 = __shfl(S, (J) + 3);            \
        const int t4 = __shfl(S, (J) + 4), t5 = __shfl(S, (J) + 5);            \
        const int t6 = __shfl(S, (J) + 6), t7 = __shfl(S, (J) + 7);            \
        const float u0 = (float)x[t0 * 64 + f], u1 = (float)x[t1 * 64 + f];    \
        const float u2 = (float)x[t2 * 64 + f], u3 = (float)x[t3 * 64 + f];    \
        const float u4 = (float)x[t4 * 64 + f], u5 = (float)x[t5 * 64 + f];    \
        const float u6 = (float)x[t6 * 64 + f], u7 = (float)x[t7 * 64 + f];    \
        ACC += ((u0 + u1) + (u2 + u3)) + ((u4 + u5) + (u6 + u7));              \
    }

// one dual-stream row pair: rows r0w+I (A) and r0w+I+4 (B); stores into the
// wave's OWN LDS region rows I and I+4 (no cross-wave sharing).
#define ROWPAIR(I, SA, CA, DA, OA, SB, CB, DB, OB)                             \
    {                                                                          \
        float accA = (float)x[(r0w + I) * 64 + f];                             \
        float accB = (float)x[(r0w + I + 4) * 64 + f];                         \
        const int cmax = (CA) > (CB) ? (CA) : (CB);                            \
        for (int j = 0; j < cmax; j += 8) {                                    \
            if (j < (CA)) { G8(SA, j, accA) }                                  \
            if (j < (CB)) { G8(SB, j, accB) }                                  \
        }                                                                      \
        if ((DA) > 64 || (DB) > 64) {       /* rare long rows */               \
            for (int base = 64; base < (DA) || base < (DB); base += 64) {      \
                const int ra = (DA) - base, rb2 = (DB) - base;                 \
                const int ca2 = ra <= 0 ? 0 : (ra < 64 ? ra : 64);             \
                const int cb2 = rb2 <= 0 ? 0 : (rb2 < 64 ? rb2 : 64);          \
                int sA2 = N_NODES, sB2 = N_NODES;                              \
                if (f < ca2) sA2 = csr[(OA) + base + f];                       \
                if (f < cb2) sB2 = csr[(OB) + base + f];                       \
                const int cm2 = ca2 > cb2 ? ca2 : cb2;                         \
                for (int j = 0; j < cm2; j += 8) {                             \
                    if (j < ca2) { G8(sA2, j, accA) }                          \
                    if (j < cb2) { G8(sB2, j, accB) }                          \
                }                                                              \
            }                                                                  \
        }                                                                      \
        hsw[half][I][lane]     = (bf16_t)accA;                                 \
        hsw[half][I + 4][lane] = (bf16_t)accB;                                 \
    }

// ---------------------------------------------------------------------------
// Fused gather + MLP, BARRIER-FREE: each wave owns 8 rows end-to-end.
// MFMA tile is 16 rows; rows 8-15 are garbage (uninitialized LDS) and are
// confined: computed but never stored/pooled. No __syncthreads anywhere --
// intra-wave LDS write->read ordering is compiler-enforced (lgkmcnt).
// ---------------------------------------------------------------------------
template <int POOL>
__global__ void gmlp_kernel(const bf16_t* __restrict__ x,
                            const int* __restrict__ offset,
                            const int* __restrict__ csr,
                            const bf16_t* __restrict__ wf,   // [m*8+fi][lane][8] bf16
                            const float* __restrict__ ba, const float* __restrict__ bb,
                            bf16_t* __restrict__ xout,
                            const int* __restrict__ batch,
                            float* __restrict__ gsum) {
    __shared__ __align__(16) bf16_t hsw[2][16][72];   // per-wave: agg rows, then h2
    __shared__ __align__(16) bf16_t h2w[2][16][72];   // per-wave: h1 (GEMM1 out)

    const int tid  = threadIdx.x;
    const int half = tid >> 6;          // wave id 0..1 (fully independent)
    const int lane = tid & 63;
    const int l15  = lane & 15;
    const int quad = lane >> 4;

    const int r0w = blockIdx.x * 16 + half * 8;   // this wave's first row
    const int f   = lane;

    // prefetch the 9 offsets this wave needs, broadcast via shfl
    int offv = 0;
    if (lane < 9) offv = offset[r0w + lane];
    const int o0 = __shfl(offv, 0), o1 = __shfl(offv, 1), o2 = __shfl(offv, 2);
    const int o3 = __shfl(offv, 3), o4 = __shfl(offv, 4), o5 = __shfl(offv, 5);
    const int o6 = __shfl(offv, 6), o7 = __shfl(offv, 7), o8 = __shfl(offv, 8);
    const int d0 = o1 - o0, d1 = o2 - o1, d2 = o3 - o2, d3 = o4 - o3;
    const int d4 = o5 - o4, d5 = o6 - o5, d6 = o7 - o6, d7 = o8 - o7;
    const int c0 = d0 < 64 ? d0 : 64, c1 = d1 < 64 ? d1 : 64;
    const int c2 = d2 < 64 ? d2 : 64, c3 = d3 < 64 ? d3 : 64;
    const int c4 = d4 < 64 ? d4 : 64, c5 = d5 < 64 ? d5 : 64;
    const int c6 = d6 < 64 ? d6 : 64, c7 = d7 < 64 ? d7 : 64;

    // preload all 8 rows' first-chunk csr index vectors (8 coalesced loads in flight)
    int s0 = N_NODES, s1 = N_NODES, s2 = N_NODES, s3 = N_NODES;
    int s4 = N_NODES, s5 = N_NODES, s6 = N_NODES, s7 = N_NODES;
    if (f < c0) s0 = csr[o0 + f];
    if (f < c1) s1 = csr[o1 + f];
    if (f < c2) s2 = csr[o2 + f];
    if (f < c3) s3 = csr[o3 + f];
    if (f < c4) s4 = csr[o4 + f];
    if (f < c5) s5 = csr[o5 + f];
    if (f < c6) s6 = csr[o6 + f];
    if (f < c7) s7 = csr[o7 + f];

    // ---- gather 8 rows into hsw[half] rows 0..7 (pairs (i, i+4)) ----
    ROWPAIR(0, s0, c0, d0, o0, s4, c4, d4, o4)
    ROWPAIR(1, s1, c1, d1, o1, s5, c5, d5, o5)
    ROWPAIR(2, s2, c2, d2, o2, s6, c6, d6, o6)
    ROWPAIR(3, s3, c3, d3, o3, s7, c7, d7, o7)

    // ---- GEMM1: read hsw[half] (rows 8-15 garbage), write relu -> h2w[half] ----
    {
        bf16x8 af[2];
#pragma unroll
        for (int ks = 0; ks < 2; ++ks)
            af[ks] = *(const bf16x8*)(&hsw[half][l15][ks * 32 + quad * 8]);
#pragma unroll
        for (int ct = 0; ct < 4; ++ct) {
            const bf16x8 b0 = *(const bf16x8*)(wf + (0 * 8 + ct * 2 + 0) * 512 + lane * 8);
            const bf16x8 b1 = *(const bf16x8*)(wf + (0 * 8 + ct * 2 + 1) * 512 + lane * 8);
            f32x4 acc = {0.f, 0.f, 0.f, 0.f};
            acc = __builtin_amdgcn_mfma_f32_16x16x32_bf16(af[0], b0, acc, 0, 0, 0);
            acc = __builtin_amdgcn_mfma_f32_16x16x32_bf16(af[1], b1, acc, 0, 0, 0);
            const float bv = ba[ct * 16 + l15];
#pragma unroll
            for (int r = 0; r < 4; ++r) {
                float h = acc[r] + bv;
                h = h > 0.f ? h : 0.f;
                h2w[half][quad * 4 + r][ct * 16 + l15] = (bf16_t)h;
            }
        }
    }

    // ---- GEMM2: read h2w[half], write relu -> hsw[half] ----
    {
        bf16x8 a2[2];
#pragma unroll
        for (int ks = 0; ks < 2; ++ks)
            a2[ks] = *(const bf16x8*)(&h2w[half][l15][ks * 32 + quad * 8]);
#pragma unroll
        for (int ct = 0; ct < 4; ++ct) {
            const bf16x8 b0 = *(const bf16x8*)(wf + (1 * 8 + ct * 2 + 0) * 512 + lane * 8);
            const bf16x8 b1 = *(const bf16x8*)(wf + (1 * 8 + ct * 2 + 1) * 512 + lane * 8);
            f32x4 acc = {0.f, 0.f, 0.f, 0.f};
            acc = __builtin_amdgcn_mfma_f32_16x16x32_bf16(a2[0], b0, acc, 0, 0, 0);
            acc = __builtin_amdgcn_mfma_f32_16x16x32_bf16(a2[1], b1, acc, 0, 0, 0);
            const float bv = bb[ct * 16 + l15];
#pragma unroll
            for (int r = 0; r < 4; ++r) {
                float h = acc[r] + bv;
                h = h > 0.f ? h : 0.f;
                hsw[half][quad * 4 + r][ct * 16 + l15] = (bf16_t)h;
            }
        }
    }

    if (POOL) {
        // segmented mean-pool numerator: wave scans its own 8 rows
        int cur = -1;
        float acc = 0.f;
        for (int r = 0; r < 8; ++r) {
            const int row = r0w + r;
            const int g = batch[row];           // wave-uniform
            const float v = (float)hsw[half][r][lane];
            if (g != cur) {
                if (cur >= 0) unsafeAtomicAdd(gsum + cur * 64 + lane, acc);
                acc = 0.f;
                cur = g;
            }
            acc += v;
        }
        if (cur >= 0) unsafeAtomicAdd(gsum + cur * 64 + lane, acc);
    } else {
        // wave stores its 8 real rows: one bf16x8 per lane
        const int row8 = lane >> 3;             // 0..7
        const int colg = (lane & 7) * 8;
        const bf16x8 v = *(const bf16x8*)&hsw[half][row8][colg];
        *(bf16x8*)(xout + (r0w + row8) * 64 + colg) = v;
    }
}

// out[g][c] = (gsum[g]/max(cnt,1)) . wc[:,c] + bc[c]; cnt via binary search
__global__ void cls_kernel(const float* __restrict__ gsum,
                           const int* __restrict__ batch,
                           const float* __restrict__ wc, const float* __restrict__ bc,
                           float* __restrict__ out) {
    const int g = blockIdx.x;
    const int c = threadIdx.x;
    if (c >= N_CLS) return;
    int lo = 0, hi = N_NODES;
    while (lo < hi) { const int m = (lo + hi) >> 1; if (batch[m] < g) lo = m + 1; else hi = m; }
    const int lb = lo;
    lo = 0; hi = N_NODES;
    while (lo < hi) { const int m = (lo + hi) >> 1; if (batch[m] <= g) lo = m + 1; else hi = m; }
    const int cnt = lo - lb;
    const float inv = 1.f / (float)(cnt > 1 ? cnt : 1);
    float acc = bc[c];
    for (int k = 0; k < 64; ++k)
        acc += gsum[g * 64 + k] * inv * wc[k * N_CLS + c];
    out[g * N_CLS + c] = acc;
}

// ---------------------------------------------------------------------------
extern "C" void kernel_launch(void* const* d_in, const int* in_sizes, int n_in,
                              void* d_out, int out_size, void* d_ws, size_t ws_size,
                              hipStream_t stream) {
    const float* x   = (const float*)d_in[0];
    const float* w1a = (const float*)d_in[1];
    const float* b1a = (const float*)d_in[2];
    const float* w1b = (const float*)d_in[3];
    const float* b1b = (const float*)d_in[4];
    const float* w2a = (const float*)d_in[5];
    const float* b2a = (const float*)d_in[6];
    const float* w2b = (const float*)d_in[7];
    const float* b2b = (const float*)d_in[8];
    const float* w3a = (const float*)d_in[9];
    const float* b3a = (const float*)d_in[10];
    const float* w3b = (const float*)d_in[11];
    const float* b3b = (const float*)d_in[12];
    const float* wc  = (const float*)d_in[13];
    const float* bc  = (const float*)d_in[14];
    const int*   ei    = (const int*)d_in[15];
    const int*   batch = (const int*)d_in[16];
    float* out = (float*)d_out;

    // workspace layout (~50.1 MB, 16B-aligned; feature buffers have +128B zero pad row)
    char*   ws     = (char*)d_ws;
    int*    bcnt   = (int*)ws;                      // 391 ints (pad 1568)
    int*    offset = (int*)(ws + 3136);             // N+1 ints (pad 400016)
    int*    csr    = (int*)(ws + 403152);           // E ints = 4,800,000
    int*    bpair  = (int*)(ws + 5203152);          // 391*4096*4 = 6,406,144
    bf16_t* xbf    = (bf16_t*)(ws + 11609296);      // 12,800,128 (incl pad row)
    bf16_t* h      = (bf16_t*)(ws + 24409424);      // 12,800,128
    bf16_t* xA     = (bf16_t*)(ws + 37209552);      // 12,800,128
    float*  gsum   = (float*)(ws + 50009680);       // 32,768
    bf16_t* wfragG = (bf16_t*)(ws + 50042448);      // 3*2*8*512 bf16 = 49,152 B

    // zero bucket counters (capture-safe memset node)
    hipMemsetAsync(bcnt, 0, NBUCK * sizeof(int), stream);

    // fused prep: x->bf16 stream + binA binning (+ gsum/pads zero, wfrag pack)
    prep_kernel<<<TOBF_BLKS + BINA_BLKS, 512, 0, stream>>>(
        x, xbf, bcnt, gsum, w1a, w1b, w2a, w2b, w3a, w3b, wfragG, h, xA, ei, bpair);

    // per-bucket counting sort (1024 threads for latency hiding at 391 blocks)
    sortfill_kernel<<<NBUCK, 1024, 0, stream>>>(bpair, bcnt, offset, csr);

    // fused gather+MLP layers (ping-pong buffers: xbf -> xA -> h -> pool)
    gmlp_kernel<0><<<NTILES, 128, 0, stream>>>(xbf, offset, csr, wfragG,         b1a, b1b, xA, nullptr, nullptr);
    gmlp_kernel<0><<<NTILES, 128, 0, stream>>>(xA,  offset, csr, wfragG + 8192,  b2a, b2b, h,  nullptr, nullptr);
    gmlp_kernel<1><<<NTILES, 128, 0, stream>>>(h,   offset, csr, wfragG + 16384, b3a, b3b, nullptr, batch, gsum);

    // classify
    cls_kernel<<<N_GRAPH, 64, 0, stream>>>(gsum, batch, wc, bc, out);
}

// Round 12
// 268.105 us; speedup vs baseline: 1.0048x; 1.0048x over previous
//
#include <hip/hip_runtime.h>
#include <hip/hip_bf16.h>

// GIN: 3x fused [CSR gather-sum + MLP(64->64->64) + relu] + mean-pool(128) + linear(64->10)
// v12:
//  gmlp = v10 body (best measured: 46.4us, 2.63 TB/s, VGPR 32; r11 barrier-free was
//   neutral-to-worse -> reverted) + CACHE-POLLUTION CONTROL:
//   - xout writes via __builtin_nontemporal_store (no L2 allocate: removes
//     12.8 MB/layer of x-row evictions; x reuse is the gather's only latency lever)
//   - csr index reads via __builtin_nontemporal_load (read-once 4.8 MB stream)
//   Theory: BW = 0.044 TB/s x occupancy invariant (r2-r11) = per-request latency
//   bound; higher x L2-hit rate is the only unaddressed latency term.
//  prep: tobf + binA fused (r11, neutral but one less dispatch); bcnt via memset.
//  sortfill: 1024 threads (r11). 7 dispatches.

#define N_NODES 100000
#define N_EDGES 1200000
#define N_GRAPH 128
#define N_CLS   10
#define NBUCK   391        // dst >> 8
#define BCAP    4096       // per-bucket capacity (mean 3070, +18 sigma)
#define BSH     12         // log2(BCAP)
#define NTILES  6250       // N_NODES / 16
#define TOBF_BLKS 1563     // ceil(N_NODES*64 / (512*8))
#define BINA_BLKS 586      // ceil(N_EDGES/4 / 512)

typedef __bf16 bf16_t;
typedef __bf16 bf16x8 __attribute__((ext_vector_type(8)));
typedef float  f32x4  __attribute__((ext_vector_type(4)));

// ---------------- prep: x->bf16 + binA fused (+ gsum/pads zero, wfrag pack) ----------------
__global__ void prep_kernel(const float* __restrict__ x, bf16_t* __restrict__ xb,
                            int* __restrict__ bcnt, float* __restrict__ gsum,
                            const float* __restrict__ w1a, const float* __restrict__ w1b,
                            const float* __restrict__ w2a, const float* __restrict__ w2b,
                            const float* __restrict__ w3a, const float* __restrict__ w3b,
                            bf16_t* __restrict__ wfragG,
                            bf16_t* __restrict__ hPad, bf16_t* __restrict__ xAPad,
                            const int* __restrict__ ei, int* __restrict__ bpair) {
    __shared__ int lcnt[NBUCK];
    __shared__ int lbase[NBUCK];
    const int tid = threadIdx.x;
    const int blk = blockIdx.x;

    if (blk >= TOBF_BLKS) {
        // ---- binA role (bcnt pre-zeroed by hipMemsetAsync) ----
        for (int b = tid; b < NBUCK; b += 512) lcnt[b] = 0;
        __syncthreads();
        const int e0 = ((blk - TOBF_BLKS) * 512 + tid) * 4;
        int4 s4, d4; int b[4], r[4];
        const bool valid = e0 < N_EDGES;           // N_EDGES % 4 == 0
        if (valid) {
            s4 = *(const int4*)(ei + e0);
            d4 = *(const int4*)(ei + N_EDGES + e0);
            b[0] = d4.x >> 8; b[1] = d4.y >> 8; b[2] = d4.z >> 8; b[3] = d4.w >> 8;
            r[0] = atomicAdd(&lcnt[b[0]], 1);
            r[1] = atomicAdd(&lcnt[b[1]], 1);
            r[2] = atomicAdd(&lcnt[b[2]], 1);
            r[3] = atomicAdd(&lcnt[b[3]], 1);
        }
        __syncthreads();
        for (int bb = tid; bb < NBUCK; bb += 512) {
            const int c = lcnt[bb];
            lbase[bb] = c ? atomicAdd(&bcnt[bb], c) : 0;
        }
        __syncthreads();
        if (valid) {
            const int ss[4] = {s4.x, s4.y, s4.z, s4.w};
            const int dd[4] = {d4.x, d4.y, d4.z, d4.w};
#pragma unroll
            for (int j = 0; j < 4; ++j) {
                const int slot = lbase[b[j]] + r[j];
                if (slot < BCAP)
                    bpair[(b[j] << BSH) + slot] = (ss[j] << 8) | (dd[j] & 255);
            }
        }
        return;
    }

    // ---- special roles (blocks 0..3 also convert their x slice) ----
    if (blk == 0) {
        f32x4* g4 = (f32x4*)gsum;
        for (int i = tid; i < N_GRAPH * 16; i += 512)   // 8192 f32
            g4[i] = (f32x4){0.f, 0.f, 0.f, 0.f};
        if (tid < 64) {                                  // zero-pad rows (idx N_NODES)
            xb[N_NODES * 64 + tid]    = (bf16_t)0.f;
            hPad[N_NODES * 64 + tid]  = (bf16_t)0.f;
            xAPad[N_NODES * 64 + tid] = (bf16_t)0.f;
        }
    } else if (blk <= 3 && tid < 256) {
        // pack layer L's weight fragments: wfragG[((L*2+m)*8+fi)*512 + lane*8 + j]
        const int L = blk - 1;
        const float* wA = L == 0 ? w1a : (L == 1 ? w2a : w3a);
        const float* wB = L == 0 ? w1b : (L == 1 ? w2b : w3b);
        const int k  = tid >> 2;
        const int n0 = (tid & 3) << 4;
        const int ks = k >> 5, qd = (k >> 3) & 3, jj = k & 7;
        const int fi = ((n0 >> 4) << 1) + ks;
#pragma unroll
        for (int m = 0; m < 2; ++m) {
            const float* w = m ? wB : wA;
            const f32x4 v0 = *(const f32x4*)(w + k * 64 + n0);
            const f32x4 v1 = *(const f32x4*)(w + k * 64 + n0 + 4);
            const f32x4 v2 = *(const f32x4*)(w + k * 64 + n0 + 8);
            const f32x4 v3 = *(const f32x4*)(w + k * 64 + n0 + 12);
            bf16_t* dst = wfragG + ((L * 2 + m) * 8 + fi) * 512 + jj;
#pragma unroll
            for (int l = 0; l < 4; ++l) {
                dst[(qd * 16 + l) * 8]      = (bf16_t)v0[l];
                dst[(qd * 16 + 4 + l) * 8]  = (bf16_t)v1[l];
                dst[(qd * 16 + 8 + l) * 8]  = (bf16_t)v2[l];
                dst[(qd * 16 + 12 + l) * 8] = (bf16_t)v3[l];
            }
        }
    }

    // ---- tobf stream ----
    const int i = (blk * 512 + tid) * 8;
    if (i < N_NODES * 64) {
        const f32x4 a = *(const f32x4*)(x + i);
        const f32x4 b = *(const f32x4*)(x + i + 4);
        bf16x8 o;
#pragma unroll
        for (int j = 0; j < 4; ++j) { o[j] = (bf16_t)a[j]; o[4 + j] = (bf16_t)b[j]; }
        *(bf16x8*)(xb + i) = o;
    }
}

// one WG (1024 threads) per bucket: inline prefix + LDS counting sort
__global__ void sortfill_kernel(const int* __restrict__ bpair,
                                const int* __restrict__ bcnt,
                                int* __restrict__ offset, int* __restrict__ csr) {
    __shared__ int red[1024];
    __shared__ int hist[256];
    __shared__ int l[256];
    __shared__ int cursor[256];
    const int b = blockIdx.x;
    const int t = threadIdx.x;
    const int base = b << BSH;

    // prefix: cbase = sum_{i<b} min(bcnt[i],BCAP); cnt = min(bcnt[b],BCAP)
    int part = 0;
    for (int i = t; i < b; i += 1024) {
        int c = bcnt[i];
        part += (c < BCAP ? c : BCAP);
    }
    red[t] = part;
    __syncthreads();
    for (int d = 512; d > 0; d >>= 1) {
        if (t < d) red[t] += red[t + d];
        __syncthreads();
    }
    const int cbase = red[0];
    int cnt = bcnt[b];
    cnt = cnt < BCAP ? cnt : BCAP;
    if (b == NBUCK - 1 && t == 0) offset[N_NODES] = cbase + cnt;
    __syncthreads();

    if (t < 256) hist[t] = 0;
    __syncthreads();
    for (int i = t; i < cnt; i += 1024)
        atomicAdd(&hist[bpair[base + i] & 255], 1);
    __syncthreads();

    int v = 0;
    if (t < 256) { v = hist[t]; l[t] = v; }
    __syncthreads();
    for (int d = 1; d < 256; d <<= 1) {
        int u = 0;
        if (t < 256) { u = l[t]; if (t >= d) u += l[t - d]; }
        __syncthreads();
        if (t < 256) l[t] = u;
        __syncthreads();
    }
    if (t < 256) {
        const int gpos = cbase + l[t] - v;          // exclusive
        const int node = (b << 8) + t;
        if (node < N_NODES) offset[node] = gpos;
        cursor[t] = gpos;
    }
    __syncthreads();

    for (int i = t; i < cnt; i += 1024) {
        const int p = bpair[base + i];
        const int pos = atomicAdd(&cursor[p & 255], 1);
        csr[pos] = p >> 8;
    }
}

// ---------------------------------------------------------------------------
// Unmasked 8-deep gather group. Indices beyond a row's count are N_NODES ->
// the zero pad row (L1-hot, contributes 0). x loads are NORMAL (cacheable --
// they are the reuse candidates we're protecting).
// ---------------------------------------------------------------------------
#define G8(S, J, ACC)                                                          \
    {                                                                          \
        const int t0 = __shfl(S, (J) + 0), t1 = __shfl(S, (J) + 1);            \
        const int t2 = __shfl(S, (J) + 2), t3 = __shfl(S, (J) + 3);            \
        const int t4 = __shfl(S, (J) + 4), t5 = __shfl(S, (J) + 5);            \
        const int t6 = __shfl(S, (J) + 6), t7 = __shfl(S, (J) + 7);            \
        const float u0 = (float)x[t0 * 64 + f], u1 = (float)x[t1 * 64 + f];    \
        const float u2 = (float)x[t2 * 64 + f], u3 = (float)x[t3 * 64 + f];    \
        const float u4 = (float)x[t4 * 64 + f], u5 = (float)x[t5 * 64 + f];    \
        const float u6 = (float)x[t6 * 64 + f], u7 = (float)x[t7 * 64 + f];    \
        ACC += ((u0 + u1) + (u2 + u3)) + ((u4 + u5) + (u6 + u7));              \
    }

// one dual-stream row pair: rows r0w+I (A) and r0w+I+4 (B)
// csr reloads for long rows are nontemporal (read-once stream).
#define ROWPAIR(I, SA, CA, DA, OA, SB, CB, DB, OB)                             \
    {                                                                          \
        float accA = (float)x[(r0w + I) * 64 + f];                             \
        float accB = (float)x[(r0w + I + 4) * 64 + f];                         \
        const int cmax = (CA) > (CB) ? (CA) : (CB);                            \
        for (int j = 0; j < cmax; j += 8) {                                    \
            if (j < (CA)) { G8(SA, j, accA) }                                  \
            if (j < (CB)) { G8(SB, j, accB) }                                  \
        }                                                                      \
        if ((DA) > 64 || (DB) > 64) {       /* rare long rows */               \
            for (int base = 64; base < (DA) || base < (DB); base += 64) {      \
                const int ra = (DA) - base, rb2 = (DB) - base;                 \
                const int ca2 = ra <= 0 ? 0 : (ra < 64 ? ra : 64);             \
                const int cb2 = rb2 <= 0 ? 0 : (rb2 < 64 ? rb2 : 64);          \
                int sA2 = N_NODES, sB2 = N_NODES;                              \
                if (f < ca2) sA2 = __builtin_nontemporal_load(csr + (OA) + base + f); \
                if (f < cb2) sB2 = __builtin_nontemporal_load(csr + (OB) + base + f); \
                const int cm2 = ca2 > cb2 ? ca2 : cb2;                         \
                for (int j = 0; j < cm2; j += 8) {                             \
                    if (j < ca2) { G8(sA2, j, accA) }                          \
                    if (j < cb2) { G8(sB2, j, accB) }                          \
                }                                                              \
            }                                                                  \
        }                                                                      \
        hs[half * 8 + I][lane]     = (bf16_t)accA;                             \
        hs[half * 8 + I + 4][lane] = (bf16_t)accB;                             \
    }

// ---------------------------------------------------------------------------
// Fused gather + MLP, one 16-row tile per 128-thread block (2 waves). (= v10)
// ---------------------------------------------------------------------------
template <int POOL>
__global__ void gmlp_kernel(const bf16_t* __restrict__ x,
                            const int* __restrict__ offset,
                            const int* __restrict__ csr,
                            const bf16_t* __restrict__ wf,   // [m*8+fi][lane][8] bf16
                            const float* __restrict__ ba, const float* __restrict__ bb,
                            bf16_t* __restrict__ xout,
                            const int* __restrict__ batch,
                            float* __restrict__ gsum) {
    __shared__ __align__(16) bf16_t hs[16][72];   // agg rows, then h2 (final)
    __shared__ __align__(16) bf16_t h2[16][72];   // h1 (GEMM1 out)

    const int tid  = threadIdx.x;
    const int half = tid >> 6;          // 0..1
    const int lane = tid & 63;
    const int l15  = lane & 15;
    const int quad = lane >> 4;

    const int rb  = blockIdx.x * 16;    // tile's first row (N_NODES % 16 == 0)
    const int r0w = rb + half * 8;      // this wave's first row
    const int f   = lane;

    // prefetch the 9 offsets this wave needs, broadcast via shfl
    int offv = 0;
    if (lane < 9) offv = offset[r0w + lane];
    const int o0 = __shfl(offv, 0), o1 = __shfl(offv, 1), o2 = __shfl(offv, 2);
    const int o3 = __shfl(offv, 3), o4 = __shfl(offv, 4), o5 = __shfl(offv, 5);
    const int o6 = __shfl(offv, 6), o7 = __shfl(offv, 7), o8 = __shfl(offv, 8);
    const int d0 = o1 - o0, d1 = o2 - o1, d2 = o3 - o2, d3 = o4 - o3;
    const int d4 = o5 - o4, d5 = o6 - o5, d6 = o7 - o6, d7 = o8 - o7;
    const int c0 = d0 < 64 ? d0 : 64, c1 = d1 < 64 ? d1 : 64;
    const int c2 = d2 < 64 ? d2 : 64, c3 = d3 < 64 ? d3 : 64;
    const int c4 = d4 < 64 ? d4 : 64, c5 = d5 < 64 ? d5 : 64;
    const int c6 = d6 < 64 ? d6 : 64, c7 = d7 < 64 ? d7 : 64;

    // preload all 8 rows' first-chunk csr index vectors (nontemporal: read-once)
    int s0 = N_NODES, s1 = N_NODES, s2 = N_NODES, s3 = N_NODES;
    int s4 = N_NODES, s5 = N_NODES, s6 = N_NODES, s7 = N_NODES;
    if (f < c0) s0 = __builtin_nontemporal_load(csr + o0 + f);
    if (f < c1) s1 = __builtin_nontemporal_load(csr + o1 + f);
    if (f < c2) s2 = __builtin_nontemporal_load(csr + o2 + f);
    if (f < c3) s3 = __builtin_nontemporal_load(csr + o3 + f);
    if (f < c4) s4 = __builtin_nontemporal_load(csr + o4 + f);
    if (f < c5) s5 = __builtin_nontemporal_load(csr + o5 + f);
    if (f < c6) s6 = __builtin_nontemporal_load(csr + o6 + f);
    if (f < c7) s7 = __builtin_nontemporal_load(csr + o7 + f);

    // ---- gather 8 rows into hs (pairs (i, i+4); all groups full G8) ----
    ROWPAIR(0, s0, c0, d0, o0, s4, c4, d4, o4)
    ROWPAIR(1, s1, c1, d1, o1, s5, c5, d5, o5)
    ROWPAIR(2, s2, c2, d2, o2, s6, c6, d6, o6)
    ROWPAIR(3, s3, c3, d3, o3, s7, c7, d7, o7)

    __syncthreads();   // gather done

    // ---- GEMM1: read hs, write relu -> h2; this wave owns ct = half*2 + {0,1}
    {
        bf16x8 af[2];
#pragma unroll
        for (int ks = 0; ks < 2; ++ks)
            af[ks] = *(const bf16x8*)(&hs[l15][ks * 32 + quad * 8]);
#pragma unroll
        for (int c = 0; c < 2; ++c) {
            const int ct = half * 2 + c;
            const bf16x8 b0 = *(const bf16x8*)(wf + (0 * 8 + ct * 2 + 0) * 512 + lane * 8);
            const bf16x8 b1 = *(const bf16x8*)(wf + (0 * 8 + ct * 2 + 1) * 512 + lane * 8);
            f32x4 acc = {0.f, 0.f, 0.f, 0.f};
            acc = __builtin_amdgcn_mfma_f32_16x16x32_bf16(af[0], b0, acc, 0, 0, 0);
            acc = __builtin_amdgcn_mfma_f32_16x16x32_bf16(af[1], b1, acc, 0, 0, 0);
            const float bv = ba[ct * 16 + l15];
#pragma unroll
            for (int r = 0; r < 4; ++r) {
                float h = acc[r] + bv;
                h = h > 0.f ? h : 0.f;
                h2[quad * 4 + r][ct * 16 + l15] = (bf16_t)h;
            }
        }
    }

    __syncthreads();   // h1 complete

    // ---- GEMM2: read h2, write relu -> hs
    {
        bf16x8 a2[2];
#pragma unroll
        for (int ks = 0; ks < 2; ++ks)
            a2[ks] = *(const bf16x8*)(&h2[l15][ks * 32 + quad * 8]);
#pragma unroll
        for (int c = 0; c < 2; ++c) {
            const int ct = half * 2 + c;
            const bf16x8 b0 = *(const bf16x8*)(wf + (1 * 8 + ct * 2 + 0) * 512 + lane * 8);
            const bf16x8 b1 = *(const bf16x8*)(wf + (1 * 8 + ct * 2 + 1) * 512 + lane * 8);
            f32x4 acc = {0.f, 0.f, 0.f, 0.f};
            acc = __builtin_amdgcn_mfma_f32_16x16x32_bf16(a2[0], b0, acc, 0, 0, 0);
            acc = __builtin_amdgcn_mfma_f32_16x16x32_bf16(a2[1], b1, acc, 0, 0, 0);
            const float bv = bb[ct * 16 + l15];
#pragma unroll
            for (int r = 0; r < 4; ++r) {
                float h = acc[r] + bv;
                h = h > 0.f ? h : 0.f;
                hs[quad * 4 + r][ct * 16 + l15] = (bf16_t)h;
            }
        }
    }

    __syncthreads();   // final h complete

    if (POOL) {
        // segmented mean-pool numerator: each wave scans its own 8 rows
        int cur = -1;
        float acc = 0.f;
        for (int r = 0; r < 8; ++r) {
            const int row = r0w + r;
            const int g = batch[row];           // wave-uniform
            const float v = (float)hs[half * 8 + r][lane];
            if (g != cur) {
                if (cur >= 0) unsafeAtomicAdd(gsum + cur * 64 + lane, acc);
                acc = 0.f;
                cur = g;
            }
            acc += v;
        }
        if (cur >= 0) unsafeAtomicAdd(gsum + cur * 64 + lane, acc);
    } else {
        // wave stores its 8 rows: nontemporal (no L2 allocate -- protect x lines)
        const int row16 = half * 8 + (lane >> 3);
        const int colg  = (lane & 7) * 8;
        const bf16x8 v = *(const bf16x8*)&hs[row16][colg];
        __builtin_nontemporal_store(v, (bf16x8*)(xout + (rb + row16) * 64 + colg));
    }
}

// out[g][c] = (gsum[g]/max(cnt,1)) . wc[:,c] + bc[c]; cnt via binary search
__global__ void cls_kernel(const float* __restrict__ gsum,
                           const int* __restrict__ batch,
                           const float* __restrict__ wc, const float* __restrict__ bc,
                           float* __restrict__ out) {
    const int g = blockIdx.x;
    const int c = threadIdx.x;
    if (c >= N_CLS) return;
    int lo = 0, hi = N_NODES;
    while (lo < hi) { const int m = (lo + hi) >> 1; if (batch[m] < g) lo = m + 1; else hi = m; }
    const int lb = lo;
    lo = 0; hi = N_NODES;
    while (lo < hi) { const int m = (lo + hi) >> 1; if (batch[m] <= g) lo = m + 1; else hi = m; }
    const int cnt = lo - lb;
    const float inv = 1.f / (float)(cnt > 1 ? cnt : 1);
    float acc = bc[c];
    for (int k = 0; k < 64; ++k)
        acc += gsum[g * 64 + k] * inv * wc[k * N_CLS + c];
    out[g * N_CLS + c] = acc;
}

// ---------------------------------------------------------------------------
extern "C" void kernel_launch(void* const* d_in, const int* in_sizes, int n_in,
                              void* d_out, int out_size, void* d_ws, size_t ws_size,
                              hipStream_t stream) {
    const float* x   = (const float*)d_in[0];
    const float* w1a = (const float*)d_in[1];
    const float* b1a = (const float*)d_in[2];
    const float* w1b = (const float*)d_in[3];
    const float* b1b = (const float*)d_in[4];
    const float* w2a = (const float*)d_in[5];
    const float* b2a = (const float*)d_in[6];
    const float* w2b = (const float*)d_in[7];
    const float* b2b = (const float*)d_in[8];
    const float* w3a = (const float*)d_in[9];
    const float* b3a = (const float*)d_in[10];
    const float* w3b = (const float*)d_in[11];
    const float* b3b = (const float*)d_in[12];
    const float* wc  = (const float*)d_in[13];
    const float* bc  = (const float*)d_in[14];
    const int*   ei    = (const int*)d_in[15];
    const int*   batch = (const int*)d_in[16];
    float* out = (float*)d_out;

    // workspace layout (~50.1 MB, 16B-aligned; feature buffers have +128B zero pad row)
    char*   ws     = (char*)d_ws;
    int*    bcnt   = (int*)ws;                      // 391 ints (pad 1568)
    int*    offset = (int*)(ws + 3136);             // N+1 ints (pad 400016)
    int*    csr    = (int*)(ws + 403152);           // E ints = 4,800,000
    int*    bpair  = (int*)(ws + 5203152);          // 391*4096*4 = 6,406,144
    bf16_t* xbf    = (bf16_t*)(ws + 11609296);      // 12,800,128 (incl pad row)
    bf16_t* h      = (bf16_t*)(ws + 24409424);      // 12,800,128
    bf16_t* xA     = (bf16_t*)(ws + 37209552);      // 12,800,128
    float*  gsum   = (float*)(ws + 50009680);       // 32,768
    bf16_t* wfragG = (bf16_t*)(ws + 50042448);      // 3*2*8*512 bf16 = 49,152 B

    // zero bucket counters (capture-safe memset node)
    hipMemsetAsync(bcnt, 0, NBUCK * sizeof(int), stream);

    // fused prep: x->bf16 stream + binA binning (+ gsum/pads zero, wfrag pack)
    prep_kernel<<<TOBF_BLKS + BINA_BLKS, 512, 0, stream>>>(
        x, xbf, bcnt, gsum, w1a, w1b, w2a, w2b, w3a, w3b, wfragG, h, xA, ei, bpair);

    // per-bucket counting sort (1024 threads for latency hiding at 391 blocks)
    sortfill_kernel<<<NBUCK, 1024, 0, stream>>>(bpair, bcnt, offset, csr);

    // fused gather+MLP layers (ping-pong buffers: xbf -> xA -> h -> pool)
    gmlp_kernel<0><<<NTILES, 128, 0, stream>>>(xbf, offset, csr, wfragG,         b1a, b1b, xA, nullptr, nullptr);
    gmlp_kernel<0><<<NTILES, 128, 0, stream>>>(xA,  offset, csr, wfragG + 8192,  b2a, b2b, h,  nullptr, nullptr);
    gmlp_kernel<1><<<NTILES, 128, 0, stream>>>(h,   offset, csr, wfragG + 16384, b3a, b3b, nullptr, batch, gsum);

    // classify
    cls_kernel<<<N_GRAPH, 64, 0, stream>>>(gsum, batch, wc, bc, out);
}